// Round 1
// baseline (1647.143 us; speedup 1.0000x reference)
//
#include <hip/hip_runtime.h>

typedef __attribute__((ext_vector_type(8))) short v8s;
typedef __attribute__((ext_vector_type(4))) float v4f;
typedef __attribute__((ext_vector_type(4))) int v4i;

#define SCALE_Q 0.1767766952966369f

__device__ inline short bf_rne(float x){
  unsigned u = __builtin_bit_cast(unsigned, x);
  u += 0x7fffu + ((u >> 16) & 1u);
  return (short)(u >> 16);
}
// pack two f32 -> two bf16 (truncation; 1 v_perm_b32)
__device__ inline unsigned pkt(float lo, float hi){
  return (__builtin_bit_cast(unsigned, lo) >> 16) | (__builtin_bit_cast(unsigned, hi) & 0xffff0000u);
}
__device__ inline void async16(void* lds, const void* g){
  __builtin_amdgcn_global_load_lds((const __attribute__((address_space(1))) unsigned*)g,
                                   (__attribute__((address_space(3))) unsigned*)lds, 16, 0, 0);
}

// ---------------- prep: weight packing + bias table + nuclei copy ----------------
__global__ __launch_bounds__(256) void prep_k(
    const float* __restrict__ mask, const float* __restrict__ rpb, const int* __restrict__ rel,
    const float* __restrict__ qkv_w, const float* __restrict__ qkv_b,
    const float* __restrict__ qkv_y_w, const float* __restrict__ qkv_y_b,
    const float* __restrict__ pqx_w, const float* __restrict__ pqx_b,
    const float* __restrict__ pqy_w, const float* __restrict__ pqy_b,
    const float* __restrict__ proj_w, const float* __restrict__ proj_y_w,
    const float* __restrict__ nuclei,
    short* __restrict__ Wxt, short* __restrict__ Wyt,
    short* __restrict__ Pwt, short* __restrict__ Pywt,
    float* __restrict__ bx, float* __restrict__ by,
    float* __restrict__ bias2, float* __restrict__ nuc_out)
{
  int idx = blockIdx.x * 256 + threadIdx.x;
  if (idx < 393216){                       // Wxt / Wyt : [768][256] bf16, q-part scaled
    int which = idx >= 196608;
    int e = which ? idx - 196608 : idx;
    int n = e >> 8, k = e & 255;
    const float* pw = which ? pqy_w : pqx_w;
    const float* qw = which ? qkv_y_w : qkv_w;
    float v = (n < 256) ? pw[k*256 + n] * SCALE_Q : qw[k*512 + (n - 256)];
    (which ? Wyt : Wxt)[e] = bf_rne(v);
  } else if (idx < 524288){                // Pwt / Pywt : [256][256] bf16 transposed
    int e = idx - 393216;
    int which = e >= 65536;
    int e2 = e & 65535;
    int n = e2 >> 8, k = e2 & 255;
    const float* w = which ? proj_y_w : proj_w;
    (which ? Pywt : Pwt)[e2] = bf_rne(w[k*256 + n]);
  } else if (idx < 525824){                // bx / by : f32[768]
    int e = idx - 524288;
    int which = e >= 768;
    int n = which ? e - 768 : e;
    float v = (n < 256) ? (which ? pqy_b : pqx_b)[n] * SCALE_Q
                        : (which ? qkv_y_b : qkv_b)[n - 256];
    (which ? by : bx)[n] = v;
  } else if (idx < 1755136){               // bias2[w][h][i*49+j] = mask + rpb
    int e = idx - 525824;
    int w = e / 19208;
    int rm = e - w*19208;
    int h = rm / 2401;
    int ij = rm - h*2401;
    bias2[e] = mask[w*2401 + ij] + rpb[rel[ij]*8 + h];
  } else if (idx < 1955840){               // nuclei passthrough output
    int e = idx - 1755136;
    nuc_out[e] = nuclei[e];
  }
}

// ---------------- GEMM1: A f32 [M][256], Bt bf16 [768][256], C bf16 [M][768] ----------------
__global__ __launch_bounds__(256) void gemm_qkv_k(const float* __restrict__ A,
                                                  const short* __restrict__ Bt,
                                                  const float* __restrict__ bias,
                                                  short* __restrict__ C)
{
  __shared__ float As[128*32];   // f32, rows of 32 (128B), XOR-swizzled 16B granules
  __shared__ short Bs[128*32];   // bf16, rows of 32 (64B), XOR-swizzled 16B granules
  const int tid = threadIdx.x, lane = tid & 63, wv = tid >> 6;
  const int quad = lane >> 4, l15 = lane & 15;
  const int bid = blockIdx.x;
  const int tn = bid % 6, tm = bid / 6;
  const int wm = wv >> 1, wn = wv & 1;
  const v4f vzero = {0.f, 0.f, 0.f, 0.f};
  v4f acc[4][4];
  #pragma unroll
  for (int i = 0; i < 4; ++i)
    #pragma unroll
    for (int j = 0; j < 4; ++j) acc[i][j] = vzero;

  const size_t abase = (size_t)tm * 128 * 256;
  const size_t bbase = (size_t)tn * 128 * 256;

  for (int kk = 0; kk < 8; ++kk){
    const int k0 = kk * 32;
    #pragma unroll
    for (int j = 0; j < 4; ++j){           // A: 128 rows x 32 f32; 8 rows/instr
      int r = wv*32 + j*8 + (lane >> 3);
      int c = (lane & 7) ^ (r & 7);
      async16(&As[(wv*32 + j*8)*32], A + abase + (size_t)r*256 + k0 + c*4);
    }
    #pragma unroll
    for (int j = 0; j < 2; ++j){           // B: 128 rows x 32 bf16; 16 rows/instr
      int n = wv*32 + j*16 + (lane >> 2);
      int c = (lane & 3) ^ ((n >> 1) & 3);
      async16(&Bs[(wv*32 + j*16)*32], Bt + bbase + (size_t)n*256 + k0 + c*8);
    }
    __syncthreads();
    v8s af[4], bf[4];
    #pragma unroll
    for (int it = 0; it < 4; ++it){
      int rA = wm*64 + it*16 + l15;
      int s = rA & 7;
      const float4 x0 = *(const float4*)&As[rA*32 + (((2*quad    ) ^ s) << 2)];
      const float4 x1 = *(const float4*)&As[rA*32 + (((2*quad + 1) ^ s) << 2)];
      v4i t = { (int)pkt(x0.x, x0.y), (int)pkt(x0.z, x0.w),
                (int)pkt(x1.x, x1.y), (int)pkt(x1.z, x1.w) };
      af[it] = __builtin_bit_cast(v8s, t);
    }
    #pragma unroll
    for (int jt = 0; jt < 4; ++jt){
      int rB = wn*64 + jt*16 + l15;
      bf[jt] = *(const v8s*)&Bs[rB*32 + ((quad ^ ((rB >> 1) & 3)) << 3)];
    }
    #pragma unroll
    for (int it = 0; it < 4; ++it)
      #pragma unroll
      for (int jt = 0; jt < 4; ++jt)
        acc[it][jt] = __builtin_amdgcn_mfma_f32_16x16x32_bf16(af[it], bf[jt], acc[it][jt], 0, 0, 0);
    __syncthreads();
  }
  #pragma unroll
  for (int jt = 0; jt < 4; ++jt){
    const int col = tn*128 + wn*64 + jt*16 + l15;
    const float bj = bias[col];
    #pragma unroll
    for (int it = 0; it < 4; ++it){
      const int row0 = tm*128 + wm*64 + it*16 + quad*4;
      #pragma unroll
      for (int r = 0; r < 4; ++r)
        C[(size_t)(row0 + r)*768 + col] = bf_rne(acc[it][jt][r] + bj);
    }
  }
}

// ---------------- GEMM2: A bf16 [M][256], Bt bf16 [256][256], D f32 [M][256] ----------------
__global__ __launch_bounds__(256) void gemm_out_k(const short* __restrict__ A,
                                                  const short* __restrict__ Bt,
                                                  const float* __restrict__ bias,
                                                  float* __restrict__ D)
{
  __shared__ short As[128*32];
  __shared__ short Bs[128*32];
  const int tid = threadIdx.x, lane = tid & 63, wv = tid >> 6;
  const int quad = lane >> 4, l15 = lane & 15;
  const int bid = blockIdx.x;
  const int tn = bid & 1, tm = bid >> 1;
  const int wm = wv >> 1, wn = wv & 1;
  const v4f vzero = {0.f, 0.f, 0.f, 0.f};
  v4f acc[4][4];
  #pragma unroll
  for (int i = 0; i < 4; ++i)
    #pragma unroll
    for (int j = 0; j < 4; ++j) acc[i][j] = vzero;

  const size_t abase = (size_t)tm * 128 * 256;
  const size_t bbase = (size_t)tn * 128 * 256;

  for (int kk = 0; kk < 8; ++kk){
    const int k0 = kk * 32;
    #pragma unroll
    for (int j = 0; j < 2; ++j){
      int r = wv*32 + j*16 + (lane >> 2);
      int c = (lane & 3) ^ ((r >> 1) & 3);
      async16(&As[(wv*32 + j*16)*32], A + abase + (size_t)r*256 + k0 + c*8);
    }
    #pragma unroll
    for (int j = 0; j < 2; ++j){
      int n = wv*32 + j*16 + (lane >> 2);
      int c = (lane & 3) ^ ((n >> 1) & 3);
      async16(&Bs[(wv*32 + j*16)*32], Bt + bbase + (size_t)n*256 + k0 + c*8);
    }
    __syncthreads();
    v8s af[4], bf[4];
    #pragma unroll
    for (int it = 0; it < 4; ++it){
      int rA = wm*64 + it*16 + l15;
      af[it] = *(const v8s*)&As[rA*32 + ((quad ^ ((rA >> 1) & 3)) << 3)];
    }
    #pragma unroll
    for (int jt = 0; jt < 4; ++jt){
      int rB = wn*64 + jt*16 + l15;
      bf[jt] = *(const v8s*)&Bs[rB*32 + ((quad ^ ((rB >> 1) & 3)) << 3)];
    }
    #pragma unroll
    for (int it = 0; it < 4; ++it)
      #pragma unroll
      for (int jt = 0; jt < 4; ++jt)
        acc[it][jt] = __builtin_amdgcn_mfma_f32_16x16x32_bf16(af[it], bf[jt], acc[it][jt], 0, 0, 0);
    __syncthreads();
  }
  #pragma unroll
  for (int jt = 0; jt < 4; ++jt){
    const int col = tn*128 + wn*64 + jt*16 + l15;
    const float bj = bias[col];
    #pragma unroll
    for (int it = 0; it < 4; ++it){
      const int row0 = tm*128 + wm*64 + it*16 + quad*4;
      #pragma unroll
      for (int r = 0; r < 4; ++r)
        D[(size_t)(row0 + r)*256 + col] = acc[it][jt][r] + bj;
    }
  }
}

// ---------------- attention: one WG per window, 4 waves x 4 head-sides ----------------
__global__ __launch_bounds__(256) void attn_k(const short* __restrict__ qkvx,
                                              const short* __restrict__ qkvy,
                                              const float* __restrict__ bias2,
                                              const float* __restrict__ nuclei,
                                              short* __restrict__ ax,
                                              short* __restrict__ ay)
{
  __shared__ short Pl[4][64*72];   // P (exp values), rows padded to 72 bf16
  __shared__ short Vt[4][32*72];   // V^T, rows padded to 72 bf16
  __shared__ float nmsh[64];
  const int b = blockIdx.x;
  const int tid = threadIdx.x, lane = tid & 63, wv = tid >> 6;
  const int quad = lane >> 4, l15 = lane & 15;
  if (tid < 49) nmsh[tid] = nuclei[b*49 + tid];
  else if (tid < 64) nmsh[tid] = 0.f;
  __syncthreads();
  const float* b2 = bias2 + (size_t)(b & 63) * (8*2401);
  short* myP = &Pl[wv][0];
  short* myV = &Vt[wv][0];
  const v8s zf = {0,0,0,0,0,0,0,0};
  const v4f vzero = {0.f, 0.f, 0.f, 0.f};

  for (int hs = 0; hs < 4; ++hs){
    const int idx = wv*4 + hs;
    const int side = idx >> 3, h = idx & 7;
    const short* Qb = side ? qkvx : qkvy;   // attn_x uses q_y; attn_y uses q_x
    const short* Kb = side ? qkvy : qkvx;
    short* Ob = side ? ay : ax;
    const short* qrow = Qb + (size_t)b*37632 + h*32;
    const short* krow = Kb + (size_t)b*37632 + 256 + h*32;
    const short* vrow = Kb + (size_t)b*37632 + 512 + h*32;

    // V rows (lane = j), for LDS transpose
    union { v8s v[4]; short s[32]; } Vr;
    {
      const int j = lane;
      const short* vp = vrow + (size_t)j*768;
      if (j < 49){
        Vr.v[0] = *(const v8s*)(vp);
        Vr.v[1] = *(const v8s*)(vp + 8);
        Vr.v[2] = *(const v8s*)(vp + 16);
        Vr.v[3] = *(const v8s*)(vp + 24);
      } else { Vr.v[0] = zf; Vr.v[1] = zf; Vr.v[2] = zf; Vr.v[3] = zf; }
    }
    // Q, K fragments straight from global
    v8s qf[4], kf[4];
    #pragma unroll
    for (int t = 0; t < 4; ++t){
      const int i = t*16 + l15;
      qf[t] = (i < 49) ? *(const v8s*)(qrow + (size_t)i*768 + quad*8) : zf;
      kf[t] = (i < 49) ? *(const v8s*)(krow + (size_t)i*768 + quad*8) : zf;
    }
    v4f S[4][4];
    #pragma unroll
    for (int it = 0; it < 4; ++it)
      #pragma unroll
      for (int jt = 0; jt < 4; ++jt) S[it][jt] = vzero;
    #pragma unroll
    for (int it = 0; it < 4; ++it)
      #pragma unroll
      for (int jt = 0; jt < 4; ++jt)
        S[it][jt] = __builtin_amdgcn_mfma_f32_16x16x32_bf16(qf[it], kf[jt], S[it][jt], 0, 0, 0);

    // stage V^T while MFMAs run
    #pragma unroll
    for (int hd = 0; hd < 32; ++hd) myV[hd*72 + lane] = Vr.s[hd];

    // softmax in C-layout registers
    float nmj[4]; bool jv[4];
    #pragma unroll
    for (int jt = 0; jt < 4; ++jt){
      int j = jt*16 + l15;
      jv[jt] = j < 49;
      nmj[jt] = jv[jt] ? nmsh[j] : 0.f;
    }
    float rl[4][4];
    #pragma unroll
    for (int it = 0; it < 4; ++it){
      #pragma unroll
      for (int r = 0; r < 4; ++r){
        const int i = it*16 + quad*4 + r;
        const bool iv = i < 49;
        const float nmi = iv ? nmsh[i] : 0.f;
        const float* brow = b2 + h*2401 + i*49;
        float vv[4]; float vmax = -3e38f;
        #pragma unroll
        for (int jt = 0; jt < 4; ++jt){
          const int j = jt*16 + l15;
          float val = -3e38f;
          if (iv && jv[jt]) val = S[it][jt][r] + brow[j] + nmi + nmj[jt];
          vv[jt] = val;
          vmax = fmaxf(vmax, val);
        }
        #pragma unroll
        for (int m = 1; m < 16; m <<= 1) vmax = fmaxf(vmax, __shfl_xor(vmax, m, 64));
        float pv[4]; float ssum = 0.f;
        #pragma unroll
        for (int jt = 0; jt < 4; ++jt){ pv[jt] = __expf(vv[jt] - vmax); ssum += pv[jt]; }
        #pragma unroll
        for (int m = 1; m < 16; m <<= 1) ssum += __shfl_xor(ssum, m, 64);
        rl[it][r] = 1.f / ssum;
        #pragma unroll
        for (int jt = 0; jt < 4; ++jt){
          const int j = jt*16 + l15;
          myP[i*72 + j] = (iv && jv[jt]) ? bf_rne(pv[jt]) : (short)0;
        }
      }
    }
    __syncthreads();
    // O = P @ V
    v4f O[4][2];
    #pragma unroll
    for (int it = 0; it < 4; ++it){ O[it][0] = vzero; O[it][1] = vzero; }
    #pragma unroll
    for (int ks = 0; ks < 2; ++ks){
      v8s pf[4], vf[2];
      #pragma unroll
      for (int it = 0; it < 4; ++it)
        pf[it] = *(const v8s*)&myP[(it*16 + l15)*72 + ks*32 + quad*8];
      #pragma unroll
      for (int nt = 0; nt < 2; ++nt)
        vf[nt] = *(const v8s*)&myV[(nt*16 + l15)*72 + ks*32 + quad*8];
      #pragma unroll
      for (int it = 0; it < 4; ++it)
        #pragma unroll
        for (int nt = 0; nt < 2; ++nt)
          O[it][nt] = __builtin_amdgcn_mfma_f32_16x16x32_bf16(pf[it], vf[nt], O[it][nt], 0, 0, 0);
    }
    #pragma unroll
    for (int it = 0; it < 4; ++it)
      #pragma unroll
      for (int nt = 0; nt < 2; ++nt)
        #pragma unroll
        for (int r = 0; r < 4; ++r){
          const int i = it*16 + quad*4 + r;
          if (i < 49)
            Ob[(size_t)(b*49 + i)*256 + h*32 + nt*16 + l15] = bf_rne(O[it][nt][r] * rl[it][r]);
        }
    __syncthreads();
  }
}

// ---------------- launch ----------------
extern "C" void kernel_launch(void* const* d_in, const int* in_sizes, int n_in,
                              void* d_out, int out_size, void* d_ws, size_t ws_size,
                              hipStream_t stream)
{
  const float* x       = (const float*)d_in[0];
  const float* y       = (const float*)d_in[1];
  const float* nuclei  = (const float*)d_in[2];
  const float* mask    = (const float*)d_in[3];
  const float* rpb     = (const float*)d_in[4];
  const float* qkv_w   = (const float*)d_in[5];
  const float* qkv_b   = (const float*)d_in[6];
  const float* qkv_y_w = (const float*)d_in[7];
  const float* qkv_y_b = (const float*)d_in[8];
  const float* pqx_w   = (const float*)d_in[9];
  const float* pqx_b   = (const float*)d_in[10];
  const float* pqy_w   = (const float*)d_in[11];
  const float* pqy_b   = (const float*)d_in[12];
  const float* proj_w  = (const float*)d_in[13];
  const float* proj_b  = (const float*)d_in[14];
  const float* proj_y_w= (const float*)d_in[15];
  const float* proj_y_b= (const float*)d_in[16];
  const int*   rel     = (const int*)d_in[17];

  char* ws = (char*)d_ws;
  const size_t OFF_QKVY = 308281344;            // 200704*768*2
  const size_t OFF_AX   = 616562688;
  const size_t OFF_AY   = 719323136;            // +200704*256*2
  const size_t OFF_WXT  = 822083584;
  const size_t OFF_WYT  = OFF_WXT + 393216;
  const size_t OFF_PWT  = OFF_WYT + 393216;
  const size_t OFF_PYWT = OFF_PWT + 131072;
  const size_t OFF_BX   = OFF_PYWT + 131072;
  const size_t OFF_BY   = OFF_BX + 3072;
  const size_t OFF_B2   = OFF_BY + 3072;

  short* qkvx = (short*)(ws);
  short* qkvy = (short*)(ws + OFF_QKVY);
  short* ax   = (short*)(ws + OFF_AX);
  short* ay   = (short*)(ws + OFF_AY);
  short* Wxt  = (short*)(ws + OFF_WXT);
  short* Wyt  = (short*)(ws + OFF_WYT);
  short* Pwt  = (short*)(ws + OFF_PWT);
  short* Pywt = (short*)(ws + OFF_PYWT);
  float* bx   = (float*)(ws + OFF_BX);
  float* by   = (float*)(ws + OFF_BY);
  float* bias2= (float*)(ws + OFF_B2);

  float* out   = (float*)d_out;
  float* out_y = out + 51380224;
  float* out_n = out + 102760448;

  prep_k<<<7640, 256, 0, stream>>>(mask, rpb, rel, qkv_w, qkv_b, qkv_y_w, qkv_y_b,
                                   pqx_w, pqx_b, pqy_w, pqy_b, proj_w, proj_y_w, nuclei,
                                   Wxt, Wyt, Pwt, Pywt, bx, by, bias2, out_n);
  gemm_qkv_k<<<9408, 256, 0, stream>>>(x, Wxt, bx, qkvx);
  gemm_qkv_k<<<9408, 256, 0, stream>>>(y, Wyt, by, qkvy);
  attn_k<<<4096, 256, 0, stream>>>(qkvx, qkvy, bias2, nuclei, ax, ay);
  gemm_out_k<<<3136, 256, 0, stream>>>(ax, Pwt, proj_b, out);
  gemm_out_k<<<3136, 256, 0, stream>>>(ay, Pywt, proj_y_b, out_y);
}